// Round 3
// baseline (262.748 us; speedup 1.0000x reference)
//
#include <hip/hip_runtime.h>
#include <hip/hip_fp16.h>
#include <math.h>

// ---------------------------------------------------------------------------
// GATv2 x2 + mean-pool + linear, MI355X.
// R23: filterless single-pass ELL fill. R21/R22 established: WRITE excess
//      ~= E x 29B => device-scope atomicAdds execute memory-side (coherent
//      point), NOT in XCD L2 -> the 8-way XCD partition bought no atomic
//      locality, only an 8x edge re-read (51MB) and 7/8 predicated-off fill
//      lanes. Now: each 4096-edge chunk read ONCE; 16 edges/thread with all
//      16 atomicAdds in flight before dependent stores (max MLP); interleave
//      1 fill : 8 gemm (group of 9, coprime with 8 XCDs).
//      Null branch: if fill_gemm stays ~50us -> memory-side atomic
//      throughput wall (~16G/s) is the floor; rethink construction.
//      Base = R20/R21/R22 (247-253us).
// ---------------------------------------------------------------------------

#define ELLC    48
#define OVF_CAP 65536
#define ECHUNK  4096          // edges per fill block (read once)

typedef int      vint4 __attribute__((ext_vector_type(4)));
typedef _Float16 half4 __attribute__((ext_vector_type(4)));
typedef float    f32x4 __attribute__((ext_vector_type(4)));

// ---------------- slim dual GEMM body: xl = X*Wl + bl (fp16), xr = X*Wr + br
#define GROWS 32
template <typename T>
__device__ __forceinline__ void dual_gemm_slim(
    int bid, int t,
    const T* __restrict__ X,
    const float* __restrict__ Wl, const float* __restrict__ bl,
    const float* __restrict__ Wr, const float* __restrict__ br,
    _Float16* __restrict__ xl, float* __restrict__ xr, int n,
    float* xS) {
    int row0 = bid * GROWS;
    for (int i = t; i < GROWS * 16; i += 256) {
        int r = row0 + (i >> 4);
        f32x4 v;
        v[0] = 0.f; v[1] = 0.f; v[2] = 0.f; v[3] = 0.f;
        if (r < n) {
            if constexpr (sizeof(T) == 2) {
                half4 hv = __builtin_nontemporal_load(
                    &((const half4*)(X + (size_t)r * 64))[i & 15]);
                v[0] = (float)hv[0]; v[1] = (float)hv[1];
                v[2] = (float)hv[2]; v[3] = (float)hv[3];
            } else {
                v = __builtin_nontemporal_load(
                    &((const f32x4*)(X + (size_t)r * 64))[i & 15]);
            }
        }
        ((f32x4*)xS)[i] = v;
    }
    __syncthreads();
    int h  = t & 63;
    int rb = t >> 6;  // 0..3
    float accl[8], accr[8];
#pragma unroll
    for (int i = 0; i < 8; ++i) { accl[i] = 0.f; accr[i] = 0.f; }
#pragma unroll 4
    for (int d = 0; d < 64; ++d) {
        float wl = Wl[d * 64 + h];   // coalesced 256B, L2-hot
        float wr = Wr[d * 64 + h];
#pragma unroll
        for (int i = 0; i < 8; ++i) {
            float xv = xS[(rb + 4 * i) * 64 + d];  // wave-uniform broadcast
            accl[i] += xv * wl;
            accr[i] += xv * wr;
        }
    }
    float blv = bl[h], brv = br[h];
#pragma unroll
    for (int i = 0; i < 8; ++i) {
        int r = row0 + rb + 4 * i;
        if (r < n) {
            __builtin_nontemporal_store((_Float16)(accl[i] + blv),
                                        &xl[(size_t)r * 64 + h]);
            __builtin_nontemporal_store(accr[i] + brv,
                                        &xr[(size_t)r * 64 + h]);
        }
    }
}

__global__ __launch_bounds__(256) void dual_gemm64_f16_kernel(
    const _Float16* __restrict__ X,
    const float* __restrict__ Wl, const float* __restrict__ bl,
    const float* __restrict__ Wr, const float* __restrict__ br,
    _Float16* __restrict__ xl, float* __restrict__ xr, int n) {
    __shared__ float xS[GROWS * 64];
    dual_gemm_slim<_Float16>(blockIdx.x, threadIdx.x, X, Wl, bl, Wr, br,
                             xl, xr, n, xS);
}

// ---------------- interleaved: single-pass ELL fill + layer-1 GEMM --------
// 9-block groups: r = b%9. r==0 -> fill chunk q = b/9; r>=1 -> gemm
// vg = (b/9)*8 + (r-1). 9 coprime 8 => fill blocks spread over XCDs.
__global__ __launch_bounds__(256) void fill_gemm_kernel(
    const int* __restrict__ src, const int* __restrict__ dst,
    int* __restrict__ cnt, unsigned short* __restrict__ ell,
    int* __restrict__ novf, int* __restrict__ ovf_dst, int* __restrict__ ovf_src,
    int E, int N, int fb, int ggrid,
    const float* __restrict__ X,
    const float* __restrict__ Wl, const float* __restrict__ bl,
    const float* __restrict__ Wr, const float* __restrict__ br,
    _Float16* __restrict__ xl, float* __restrict__ xr) {
    __shared__ float xS[GROWS * 64];
    int b = blockIdx.x;
    int q = b / 9, r = b % 9;
    if (r >= 1) {
        int vg = q * 8 + (r - 1);
        if (vg < ggrid)
            dual_gemm_slim<float>(vg, threadIdx.x, X, Wl, bl, Wr, br,
                                  xl, xr, N, xS);
        return;
    }
    if (q >= fb) return;
    int t  = threadIdx.x;
    int e0 = q * ECHUNK;
    int e1 = min(E, e0 + ECHUNK);
    int nq = (e1 - e0) >> 2;
    const vint4* dst4 = (const vint4*)(dst + e0);
    const vint4* src4 = (const vint4*)(src + e0);

    if (nq == (ECHUNK >> 2)) {
        // full chunk: 4 quads/thread = 16 edges. Issue ALL 16 atomicAdds
        // before any dependent store -> 16 memory-side RMWs in flight.
        vint4 dv0 = __builtin_nontemporal_load(&dst4[t]);
        vint4 dv1 = __builtin_nontemporal_load(&dst4[t + 256]);
        vint4 dv2 = __builtin_nontemporal_load(&dst4[t + 512]);
        vint4 dv3 = __builtin_nontemporal_load(&dst4[t + 768]);
        vint4 sv0 = __builtin_nontemporal_load(&src4[t]);
        vint4 sv1 = __builtin_nontemporal_load(&src4[t + 256]);
        vint4 sv2 = __builtin_nontemporal_load(&src4[t + 512]);
        vint4 sv3 = __builtin_nontemporal_load(&src4[t + 768]);
        int d[16], s[16], p[16];
#pragma unroll
        for (int j = 0; j < 4; ++j) {
            d[j]      = dv0[j]; s[j]      = sv0[j];
            d[4 + j]  = dv1[j]; s[4 + j]  = sv1[j];
            d[8 + j]  = dv2[j]; s[8 + j]  = sv2[j];
            d[12 + j] = dv3[j]; s[12 + j] = sv3[j];
        }
#pragma unroll
        for (int k = 0; k < 16; ++k) p[k] = atomicAdd(&cnt[d[k]], 1);
#pragma unroll
        for (int k = 0; k < 16; ++k) {
            if (p[k] < ELLC) {
                ell[d[k] * ELLC + p[k]] = (unsigned short)s[k];
            } else {  // P(deg>48) ~ 5e-11 per node
                int j = atomicAdd(novf, 1);
                if (j < OVF_CAP) { ovf_dst[j] = d[k]; ovf_src[j] = s[k]; }
            }
        }
    } else {
        for (int qq = t; qq < nq; qq += 256) {
            vint4 dv = __builtin_nontemporal_load(&dst4[qq]);
            vint4 sv = __builtin_nontemporal_load(&src4[qq]);
            int p0 = atomicAdd(&cnt[dv[0]], 1);
            int p1 = atomicAdd(&cnt[dv[1]], 1);
            int p2 = atomicAdd(&cnt[dv[2]], 1);
            int p3 = atomicAdd(&cnt[dv[3]], 1);
            int pp[4] = {p0, p1, p2, p3};
#pragma unroll
            for (int k = 0; k < 4; ++k) {
                if (pp[k] < ELLC) {
                    ell[dv[k] * ELLC + pp[k]] = (unsigned short)sv[k];
                } else {
                    int j = atomicAdd(novf, 1);
                    if (j < OVF_CAP) { ovf_dst[j] = dv[k]; ovf_src[j] = sv[k]; }
                }
            }
        }
        for (int e = e0 + (nq << 2) + t; e < e1; e += 256) {  // E % 4 tail
            int dd = dst[e];
            int pos = atomicAdd(&cnt[dd], 1);
            int ss  = src[e];
            if (pos < ELLC) {
                ell[dd * ELLC + pos] = (unsigned short)ss;
            } else {
                int j = atomicAdd(novf, 1);
                if (j < OVF_CAP) { ovf_dst[j] = dd; ovf_src[j] = ss; }
            }
        }
    }
}

// ---------------- per-dst GATv2 aggregation (one wave per dst) ------------
// wave = 4 groups x 16 lanes; ELL row preloaded once, indices via __shfl.
// All xl gathers for the row issued as one parallel batch (R22).
__global__ __launch_bounds__(256) void gat_aggregate_kernel(
    const _Float16* __restrict__ xl, const float* __restrict__ xr,
    const int* __restrict__ cnt, const unsigned short* __restrict__ ell,
    const int* __restrict__ novf, const int* __restrict__ ovf_dst,
    const int* __restrict__ ovf_src,
    const float* __restrict__ att, const float* __restrict__ bias,
    _Float16* __restrict__ out, int n) {
    int wid  = (blockIdx.x * blockDim.x + threadIdx.x) >> 6;
    int lane = threadIdx.x & 63;
    if (wid >= n) return;
    int g = lane >> 4;   // slot group
    int l = lane & 15;   // feature quad
    int d = wid;

    float4 att4 = ((const float4*)att)[l];
    float4 b4   = ((const float4*)bias)[l];
    int deg_d = cnt[d];
    int nd  = min(deg_d, ELLC);
    int beg = d * ELLC;

    float  s   = 0.f;
    float4 acc = make_float4(0.f, 0.f, 0.f, 0.f);

    if (deg_d > 0) {
        // one coalesced 96B read of the whole ELL row; lane i holds slot i
        int myidx = 0;
        if (lane < ELLC)
            myidx = (int)__builtin_nontemporal_load(&ell[beg + lane]);
        int i_first = __shfl(myidx, 0);

        f32x4 xrt = __builtin_nontemporal_load(
            &((const f32x4*)(xr + (size_t)d * 64))[l]);
        float4 xr4 = make_float4(xrt[0], xrt[1], xrt[2], xrt[3]);

        int niter = (nd + 7) >> 3;          // <= 6, wave-uniform

        // ---- batch prefetch: every gather in flight before any scoring ----
        half4 ph0[6], ph1[6];               // statically indexed (unrolled)
#pragma unroll
        for (int k = 0; k < 6; ++k) {
            if (k < niter) {                // wave-uniform branch
                int  sa = k * 8 + g, sb = sa + 4;
                int  i0 = __shfl(myidx, sa); if (sa >= nd) i0 = i_first;
                int  i1 = __shfl(myidx, sb); if (sb >= nd) i1 = i_first;
                ph0[k] = ((const half4*)(xl + (size_t)i0 * 64))[l];  // 8B gather
                ph1[k] = ((const half4*)(xl + (size_t)i1 * 64))[l];
            }
        }

#pragma unroll
        for (int k = 0; k < 6; ++k) {
            if (k < niter) {                // wave-uniform
                int  sa = k * 8 + g, sb = sa + 4;
                bool aa = sa < nd,   ab = sb < nd;
                half4 h0 = ph0[k];
                half4 h1 = ph1[k];
                float4 x0 = make_float4((float)h0[0], (float)h0[1], (float)h0[2], (float)h0[3]);
                float4 x1 = make_float4((float)h1[0], (float)h1[1], (float)h1[2], (float)h1[3]);
                float z, c0 = 0.f, c1 = 0.f;
                z = x0.x + xr4.x; c0 += ((z > 0.f) ? z : 0.2f * z) * att4.x;
                z = x0.y + xr4.y; c0 += ((z > 0.f) ? z : 0.2f * z) * att4.y;
                z = x0.z + xr4.z; c0 += ((z > 0.f) ? z : 0.2f * z) * att4.z;
                z = x0.w + xr4.w; c0 += ((z > 0.f) ? z : 0.2f * z) * att4.w;
                z = x1.x + xr4.x; c1 += ((z > 0.f) ? z : 0.2f * z) * att4.x;
                z = x1.y + xr4.y; c1 += ((z > 0.f) ? z : 0.2f * z) * att4.y;
                z = x1.z + xr4.z; c1 += ((z > 0.f) ? z : 0.2f * z) * att4.z;
                z = x1.w + xr4.w; c1 += ((z > 0.f) ? z : 0.2f * z) * att4.w;
#pragma unroll
                for (int sh = 8; sh >= 1; sh >>= 1) {  // 16-lane reduce
                    c0 += __shfl_xor(c0, sh);
                    c1 += __shfl_xor(c1, sh);
                }
                float w0 = aa ? __expf(fminf(c0, 30.f)) : 0.f;
                float w1 = ab ? __expf(fminf(c1, 30.f)) : 0.f;
                s += w0 + w1;
                acc.x += w0 * x0.x + w1 * x1.x;
                acc.y += w0 * x0.y + w1 * x1.y;
                acc.z += w0 * x0.z + w1 * x1.z;
                acc.w += w0 * x0.w + w1 * x1.w;
            }
        }
        // overflow fold (deg > ELLC): empty in practice
        if (deg_d > ELLC) {
            int no = min(*novf, OVF_CAP);
            for (int j = g; j < no; j += 4) {
                bool active = (ovf_dst[j] == d);
                int  i0     = active ? ovf_src[j] : i_first;
                half4 h0 = ((const half4*)(xl + (size_t)i0 * 64))[l];
                float4 x0 = make_float4((float)h0[0], (float)h0[1], (float)h0[2], (float)h0[3]);
                float z, c0 = 0.f;
                z = x0.x + xr4.x; c0 += ((z > 0.f) ? z : 0.2f * z) * att4.x;
                z = x0.y + xr4.y; c0 += ((z > 0.f) ? z : 0.2f * z) * att4.y;
                z = x0.z + xr4.z; c0 += ((z > 0.f) ? z : 0.2f * z) * att4.z;
                z = x0.w + xr4.w; c0 += ((z > 0.f) ? z : 0.2f * z) * att4.w;
#pragma unroll
                for (int sh = 8; sh >= 1; sh >>= 1) c0 += __shfl_xor(c0, sh);
                float w0 = active ? __expf(fminf(c0, 30.f)) : 0.f;
                s += w0;
                acc.x += w0 * x0.x;
                acc.y += w0 * x0.y;
                acc.z += w0 * x0.z;
                acc.w += w0 * x0.w;
            }
        }
        // merge the 4 group partial sums, xor 16 then xor 32
#pragma unroll
        for (int mask = 16; mask <= 32; mask <<= 1) {
            s     += __shfl_xor(s, mask);
            acc.x += __shfl_xor(acc.x, mask);
            acc.y += __shfl_xor(acc.y, mask);
            acc.z += __shfl_xor(acc.z, mask);
            acc.w += __shfl_xor(acc.w, mask);
        }
    }
    if (g == 0) {
        float inv = (s > 0.f) ? (1.f / s) : 0.f;   // deg-0 -> relu(bias)
        half4 hv;
        hv[0] = (_Float16)fmaxf(acc.x * inv + b4.x, 0.f);
        hv[1] = (_Float16)fmaxf(acc.y * inv + b4.y, 0.f);
        hv[2] = (_Float16)fmaxf(acc.z * inv + b4.z, 0.f);
        hv[3] = (_Float16)fmaxf(acc.w * inv + b4.w, 0.f);
        __builtin_nontemporal_store(hv, (half4*)(out + (size_t)d * 64) + l);
    }
}

// ---------------- per-graph mean pool + final linear (no atomics) ---------
// block g = graph g; batch is sorted -> binary search node range.
__global__ __launch_bounds__(256) void pool_final_kernel(
    const _Float16* __restrict__ h, const int* __restrict__ batch,
    const float* __restrict__ lin_w, const float* __restrict__ lin_b,
    float* __restrict__ out, int N, int G) {
    int g = blockIdx.x;
    int t = threadIdx.x;
    // lower_bound(batch, key)
    auto lb = [&](int key) {
        int lo = 0, hi = N;
        while (lo < hi) {
            int mid = (lo + hi) >> 1;
            if (batch[mid] < key) lo = mid + 1; else hi = mid;
        }
        return lo;
    };
    int start = lb(g), end = lb(g + 1);

    __shared__ float part[4][64];
    __shared__ float pooled[64];
    int f = t & 63, w = t >> 6;
    float acc = 0.f;
    for (int i = start + w; i < end; i += 4)          // ~25 rows/thread
        acc += (float)__builtin_nontemporal_load(&h[(size_t)i * 64 + f]);
    part[w][f] = acc;
    __syncthreads();
    if (t < 64) {
        float s = part[0][t] + part[1][t] + part[2][t] + part[3][t];
        pooled[t] = s / fmaxf((float)(end - start), 1.f);
    }
    __syncthreads();
    if (t < 32) {
        float a = 0.f;
#pragma unroll 8
        for (int hh = 0; hh < 64; ++hh) a += pooled[hh] * lin_w[hh * 32 + t];
        out[g * 32 + t] = a + lin_b[t];
    }
}

extern "C" void kernel_launch(void* const* d_in, const int* in_sizes, int n_in,
                              void* d_out, int out_size, void* d_ws, size_t ws_size,
                              hipStream_t stream) {
    const float* x     = (const float*)d_in[0];
    const int*   ei    = (const int*)d_in[1];
    const int*   batch = (const int*)d_in[2];
    const float* Wl1   = (const float*)d_in[3];
    const float* bl1   = (const float*)d_in[4];
    const float* Wr1   = (const float*)d_in[5];
    const float* br1   = (const float*)d_in[6];
    const float* att1  = (const float*)d_in[7];
    const float* bias1 = (const float*)d_in[8];
    const float* Wl2   = (const float*)d_in[9];
    const float* bl2   = (const float*)d_in[10];
    const float* Wr2   = (const float*)d_in[11];
    const float* br2   = (const float*)d_in[12];
    const float* att2  = (const float*)d_in[13];
    const float* bias2 = (const float*)d_in[14];
    const float* lin_w = (const float*)d_in[15];
    const float* lin_b = (const float*)d_in[16];
    float* out = (float*)d_out;

    const int N = in_sizes[0] / 64;
    const int E = in_sizes[1] / 2;
    const int G = out_size / 32;
    const int* src = ei;
    const int* dst = ei + E;

    // ---- workspace carve-up (256B-aligned) ----
    char*  ws  = (char*)d_ws;
    size_t off = 0;
    auto alloc = [&](size_t bytes) -> void* {
        void* p = ws + off;
        off += bytes;
        off = (off + 255) & ~(size_t)255;
        return p;
    };
    _Float16* xl   = (_Float16*)alloc((size_t)N * 64 * sizeof(_Float16));
    float* xr      = (float*)alloc((size_t)N * 64 * sizeof(float));
    _Float16* h1   = (_Float16*)alloc((size_t)N * 64 * sizeof(_Float16));  // h1/h2
    // zeroed region (contiguous): cnt, novf
    int*   cnt     = (int*)alloc((size_t)N * sizeof(int));
    int*   novf    = (int*)alloc(256);
    char*  zend    = ws + off;
    unsigned short* ell = (unsigned short*)alloc((size_t)N * ELLC * sizeof(unsigned short));
    int*   ovf_dst = (int*)alloc((size_t)OVF_CAP * sizeof(int));
    int*   ovf_src = (int*)alloc((size_t)OVF_CAP * sizeof(int));

    (void)hipMemsetAsync(cnt, 0, (size_t)(zend - (char*)cnt), stream);

    int ggrid  = (N + GROWS - 1) / GROWS;
    int agrid  = (N + 3) / 4;                    // one wave per dst node
    int nchunk = (E + ECHUNK - 1) / ECHUNK;      // fill blocks (chunk read once)
    int fb     = nchunk;
    // interleaved grid: groups of 9 = 1 fill + 8 gemm
    int ngroups = max(fb, (ggrid + 7) / 8);
    int igrid   = ngroups * 9;

    // ---- interleaved: single-pass ELL fill + layer-1 dual GEMM ----
    fill_gemm_kernel<<<igrid, 256, 0, stream>>>(
        src, dst, cnt, ell, novf, ovf_dst, ovf_src, E, N, fb, ggrid,
        x, Wl1, bl1, Wr1, br1, xl, xr);

    // ---- agg1 -> h1 (fp16) ----
    gat_aggregate_kernel<<<agrid, 256, 0, stream>>>(
        xl, xr, cnt, ell, novf, ovf_dst, ovf_src, att1, bias1, h1, N);

    // ---- layer 2 GEMM (fp16 input; h1 consumed, xl/xr overwritten) ----
    dual_gemm64_f16_kernel<<<ggrid, 256, 0, stream>>>(
        h1, Wl2, bl2, Wr2, br2, xl, xr, N);

    // ---- agg2 -> h1 (fp16, reused) ----
    gat_aggregate_kernel<<<agrid, 256, 0, stream>>>(
        xl, xr, cnt, ell, novf, ovf_dst, ovf_src, att2, bias2, h1, N);

    // ---- per-graph pool + final linear (one dispatch, no atomics) ----
    pool_final_kernel<<<G, 256, 0, stream>>>(h1, batch, lin_w, lin_b, out, N, G);
}

// Round 4
// 255.286 us; speedup vs baseline: 1.0292x; 1.0292x over previous
//
#include <hip/hip_runtime.h>
#include <hip/hip_fp16.h>
#include <math.h>

// ---------------------------------------------------------------------------
// GATv2 x2 + mean-pool + linear, MI355X.
// R24: revert to R20 structure (247us: 8-way XCD-partitioned fill, 2048-edge
//      chunks, 16 fill : 8 gemm interleave) + ONE change: cnt atomics use
//      WORKGROUP memory scope. R20's partition guarantees all writers of
//      cnt[d] are on one XCD (vb&7==b&7, round-robin dispatch), so the RMW
//      only needs XCD-L2 atomicity, not the memory-side coherent point.
//      Evidence: R21-R23 isolated a ~E x 29B WRITE excess (memory-side
//      atomic 32B write-through) and a ~19G atomics/s wall with all pipes
//      idle. L2-local atomics remove both.
//      R23 lesson (kept reverted): filterless fill raised WRITE +17MB via
//      cross-XCD ELL false sharing; partition = write ownership, 8x edge
//      re-read is L3-absorbed.
// ---------------------------------------------------------------------------

#define ELLC    48
#define OVF_CAP 65536
#define ECHUNK  2048          // edges per fill virtual block

typedef int      vint4 __attribute__((ext_vector_type(4)));
typedef _Float16 half4 __attribute__((ext_vector_type(4)));
typedef float    f32x4 __attribute__((ext_vector_type(4)));

// XCD-local (L2-executed) atomic increment. Correct ONLY because all writers
// of a given cnt[d] run on the same XCD (partition p == b&7 == XCD id).
__device__ __forceinline__ int xcd_atomic_inc(int* p) {
    return __hip_atomic_fetch_add(p, 1, __ATOMIC_RELAXED,
                                  __HIP_MEMORY_SCOPE_WORKGROUP);
}

// ---------------- slim dual GEMM body: xl = X*Wl + bl (fp16), xr = X*Wr + br
#define GROWS 32
template <typename T>
__device__ __forceinline__ void dual_gemm_slim(
    int bid, int t,
    const T* __restrict__ X,
    const float* __restrict__ Wl, const float* __restrict__ bl,
    const float* __restrict__ Wr, const float* __restrict__ br,
    _Float16* __restrict__ xl, float* __restrict__ xr, int n,
    float* xS) {
    int row0 = bid * GROWS;
    for (int i = t; i < GROWS * 16; i += 256) {
        int r = row0 + (i >> 4);
        f32x4 v;
        v[0] = 0.f; v[1] = 0.f; v[2] = 0.f; v[3] = 0.f;
        if (r < n) {
            if constexpr (sizeof(T) == 2) {
                half4 hv = __builtin_nontemporal_load(
                    &((const half4*)(X + (size_t)r * 64))[i & 15]);
                v[0] = (float)hv[0]; v[1] = (float)hv[1];
                v[2] = (float)hv[2]; v[3] = (float)hv[3];
            } else {
                v = __builtin_nontemporal_load(
                    &((const f32x4*)(X + (size_t)r * 64))[i & 15]);
            }
        }
        ((f32x4*)xS)[i] = v;
    }
    __syncthreads();
    int h  = t & 63;
    int rb = t >> 6;  // 0..3
    float accl[8], accr[8];
#pragma unroll
    for (int i = 0; i < 8; ++i) { accl[i] = 0.f; accr[i] = 0.f; }
#pragma unroll 4
    for (int d = 0; d < 64; ++d) {
        float wl = Wl[d * 64 + h];   // coalesced 256B, L2-hot
        float wr = Wr[d * 64 + h];
#pragma unroll
        for (int i = 0; i < 8; ++i) {
            float xv = xS[(rb + 4 * i) * 64 + d];  // wave-uniform broadcast
            accl[i] += xv * wl;
            accr[i] += xv * wr;
        }
    }
    float blv = bl[h], brv = br[h];
#pragma unroll
    for (int i = 0; i < 8; ++i) {
        int r = row0 + rb + 4 * i;
        if (r < n) {
            __builtin_nontemporal_store((_Float16)(accl[i] + blv),
                                        &xl[(size_t)r * 64 + h]);
            __builtin_nontemporal_store(accr[i] + brv,
                                        &xr[(size_t)r * 64 + h]);
        }
    }
}

__global__ __launch_bounds__(256) void dual_gemm64_f16_kernel(
    const _Float16* __restrict__ X,
    const float* __restrict__ Wl, const float* __restrict__ bl,
    const float* __restrict__ Wr, const float* __restrict__ br,
    _Float16* __restrict__ xl, float* __restrict__ xr, int n) {
    __shared__ float xS[GROWS * 64];
    dual_gemm_slim<_Float16>(blockIdx.x, threadIdx.x, X, Wl, bl, Wr, br,
                             xl, xr, n, xS);
}

// ---------------- interleaved: XCD-partitioned ELL fill + layer-1 GEMM ----
// 24-block groups: r = b%24. r<16 -> fill vb = (b/24)*16+r (vb&7 == b&7!);
// r>=16 -> gemm vg = (b/24)*8 + (r-16).
__global__ __launch_bounds__(256) void fill_gemm_kernel(
    const int* __restrict__ src, const int* __restrict__ dst,
    int* __restrict__ cnt, unsigned short* __restrict__ ell,
    int* __restrict__ novf, int* __restrict__ ovf_dst, int* __restrict__ ovf_src,
    int E, int N, int psize, int fb, int ggrid,
    const float* __restrict__ X,
    const float* __restrict__ Wl, const float* __restrict__ bl,
    const float* __restrict__ Wr, const float* __restrict__ br,
    _Float16* __restrict__ xl, float* __restrict__ xr) {
    __shared__ float xS[GROWS * 64];
    int b = blockIdx.x;
    int q = b / 24, r = b % 24;
    if (r >= 16) {
        int vg = q * 8 + (r - 16);
        if (vg < ggrid)
            dual_gemm_slim<float>(vg, threadIdx.x, X, Wl, bl, Wr, br,
                                  xl, xr, N, xS);
        return;
    }
    int vb = q * 16 + r;
    if (vb >= fb) return;
    int t     = threadIdx.x;
    int chunk = vb >> 3;
    int p     = vb & 7;                   // partition == XCD (== b&7)
    int d0    = p * psize;
    int d1    = min(N, d0 + psize);
    int e0    = chunk * ECHUNK;
    int e1    = min(E, e0 + ECHUNK);
    int nq    = (e1 - e0) >> 2;
    const vint4* dst4 = (const vint4*)(dst + e0);
    const vint4* src4 = (const vint4*)(src + e0);

    auto scatter4 = [&](vint4 dv, vint4 sv) {
#pragma unroll
        for (int k = 0; k < 4; ++k) {
            int d = dv[k];
            int s = sv[k];
            if (d >= d0 && d < d1) {
                int pos = xcd_atomic_inc(&cnt[d]);   // L2-local RMW
                if (pos < ELLC) {
                    ell[d * ELLC + pos] = (unsigned short)s;
                } else {  // P(deg>48) ~ 5e-11 per node
                    int j = atomicAdd(novf, 1);      // device scope (cold)
                    if (j < OVF_CAP) { ovf_dst[j] = d; ovf_src[j] = s; }
                }
            }
        }
    };

    if (nq == (ECHUNK >> 2)) {   // full chunk: both loads up front, 8 chains
        vint4 dvA = __builtin_nontemporal_load(&dst4[t]);
        vint4 svA = __builtin_nontemporal_load(&src4[t]);
        vint4 dvB = __builtin_nontemporal_load(&dst4[t + 256]);
        vint4 svB = __builtin_nontemporal_load(&src4[t + 256]);
        scatter4(dvA, svA);
        scatter4(dvB, svB);
    } else {
        for (int qq = t; qq < nq; qq += 256) {
            vint4 dv = __builtin_nontemporal_load(&dst4[qq]);
            vint4 sv = __builtin_nontemporal_load(&src4[qq]);
            scatter4(dv, sv);
        }
        for (int e = e0 + (nq << 2) + t; e < e1; e += 256) {  // E % 4 tail
            int d = dst[e];
            if (d >= d0 && d < d1) {
                int pos = xcd_atomic_inc(&cnt[d]);
                int s   = src[e];
                if (pos < ELLC) {
                    ell[d * ELLC + pos] = (unsigned short)s;
                } else {
                    int j = atomicAdd(novf, 1);
                    if (j < OVF_CAP) { ovf_dst[j] = d; ovf_src[j] = s; }
                }
            }
        }
    }
}

// ---------------- per-dst GATv2 aggregation (one wave per dst) ------------
// wave = 4 groups x 16 lanes; ELL row preloaded once, indices via __shfl.
// All xl gathers for the row issued as one parallel batch (R22, neutral).
__global__ __launch_bounds__(256) void gat_aggregate_kernel(
    const _Float16* __restrict__ xl, const float* __restrict__ xr,
    const int* __restrict__ cnt, const unsigned short* __restrict__ ell,
    const int* __restrict__ novf, const int* __restrict__ ovf_dst,
    const int* __restrict__ ovf_src,
    const float* __restrict__ att, const float* __restrict__ bias,
    _Float16* __restrict__ out, int n) {
    int wid  = (blockIdx.x * blockDim.x + threadIdx.x) >> 6;
    int lane = threadIdx.x & 63;
    if (wid >= n) return;
    int g = lane >> 4;   // slot group
    int l = lane & 15;   // feature quad
    int d = wid;

    float4 att4 = ((const float4*)att)[l];
    float4 b4   = ((const float4*)bias)[l];
    int deg_d = cnt[d];
    int nd  = min(deg_d, ELLC);
    int beg = d * ELLC;

    float  s   = 0.f;
    float4 acc = make_float4(0.f, 0.f, 0.f, 0.f);

    if (deg_d > 0) {
        // one coalesced 96B read of the whole ELL row; lane i holds slot i
        int myidx = 0;
        if (lane < ELLC)
            myidx = (int)__builtin_nontemporal_load(&ell[beg + lane]);
        int i_first = __shfl(myidx, 0);

        f32x4 xrt = __builtin_nontemporal_load(
            &((const f32x4*)(xr + (size_t)d * 64))[l]);
        float4 xr4 = make_float4(xrt[0], xrt[1], xrt[2], xrt[3]);

        int niter = (nd + 7) >> 3;          // <= 6, wave-uniform

        // ---- batch prefetch: every gather in flight before any scoring ----
        half4 ph0[6], ph1[6];               // statically indexed (unrolled)
#pragma unroll
        for (int k = 0; k < 6; ++k) {
            if (k < niter) {                // wave-uniform branch
                int  sa = k * 8 + g, sb = sa + 4;
                int  i0 = __shfl(myidx, sa); if (sa >= nd) i0 = i_first;
                int  i1 = __shfl(myidx, sb); if (sb >= nd) i1 = i_first;
                ph0[k] = ((const half4*)(xl + (size_t)i0 * 64))[l];  // 8B gather
                ph1[k] = ((const half4*)(xl + (size_t)i1 * 64))[l];
            }
        }

#pragma unroll
        for (int k = 0; k < 6; ++k) {
            if (k < niter) {                // wave-uniform
                int  sa = k * 8 + g, sb = sa + 4;
                bool aa = sa < nd,   ab = sb < nd;
                half4 h0 = ph0[k];
                half4 h1 = ph1[k];
                float4 x0 = make_float4((float)h0[0], (float)h0[1], (float)h0[2], (float)h0[3]);
                float4 x1 = make_float4((float)h1[0], (float)h1[1], (float)h1[2], (float)h1[3]);
                float z, c0 = 0.f, c1 = 0.f;
                z = x0.x + xr4.x; c0 += ((z > 0.f) ? z : 0.2f * z) * att4.x;
                z = x0.y + xr4.y; c0 += ((z > 0.f) ? z : 0.2f * z) * att4.y;
                z = x0.z + xr4.z; c0 += ((z > 0.f) ? z : 0.2f * z) * att4.z;
                z = x0.w + xr4.w; c0 += ((z > 0.f) ? z : 0.2f * z) * att4.w;
                z = x1.x + xr4.x; c1 += ((z > 0.f) ? z : 0.2f * z) * att4.x;
                z = x1.y + xr4.y; c1 += ((z > 0.f) ? z : 0.2f * z) * att4.y;
                z = x1.z + xr4.z; c1 += ((z > 0.f) ? z : 0.2f * z) * att4.z;
                z = x1.w + xr4.w; c1 += ((z > 0.f) ? z : 0.2f * z) * att4.w;
#pragma unroll
                for (int sh = 8; sh >= 1; sh >>= 1) {  // 16-lane reduce
                    c0 += __shfl_xor(c0, sh);
                    c1 += __shfl_xor(c1, sh);
                }
                float w0 = aa ? __expf(fminf(c0, 30.f)) : 0.f;
                float w1 = ab ? __expf(fminf(c1, 30.f)) : 0.f;
                s += w0 + w1;
                acc.x += w0 * x0.x + w1 * x1.x;
                acc.y += w0 * x0.y + w1 * x1.y;
                acc.z += w0 * x0.z + w1 * x1.z;
                acc.w += w0 * x0.w + w1 * x1.w;
            }
        }
        // overflow fold (deg > ELLC): empty in practice
        if (deg_d > ELLC) {
            int no = min(*novf, OVF_CAP);
            for (int j = g; j < no; j += 4) {
                bool active = (ovf_dst[j] == d);
                int  i0     = active ? ovf_src[j] : i_first;
                half4 h0 = ((const half4*)(xl + (size_t)i0 * 64))[l];
                float4 x0 = make_float4((float)h0[0], (float)h0[1], (float)h0[2], (float)h0[3]);
                float z, c0 = 0.f;
                z = x0.x + xr4.x; c0 += ((z > 0.f) ? z : 0.2f * z) * att4.x;
                z = x0.y + xr4.y; c0 += ((z > 0.f) ? z : 0.2f * z) * att4.y;
                z = x0.z + xr4.z; c0 += ((z > 0.f) ? z : 0.2f * z) * att4.z;
                z = x0.w + xr4.w; c0 += ((z > 0.f) ? z : 0.2f * z) * att4.w;
#pragma unroll
                for (int sh = 8; sh >= 1; sh >>= 1) c0 += __shfl_xor(c0, sh);
                float w0 = active ? __expf(fminf(c0, 30.f)) : 0.f;
                s += w0;
                acc.x += w0 * x0.x;
                acc.y += w0 * x0.y;
                acc.z += w0 * x0.z;
                acc.w += w0 * x0.w;
            }
        }
        // merge the 4 group partial sums, xor 16 then xor 32
#pragma unroll
        for (int mask = 16; mask <= 32; mask <<= 1) {
            s     += __shfl_xor(s, mask);
            acc.x += __shfl_xor(acc.x, mask);
            acc.y += __shfl_xor(acc.y, mask);
            acc.z += __shfl_xor(acc.z, mask);
            acc.w += __shfl_xor(acc.w, mask);
        }
    }
    if (g == 0) {
        float inv = (s > 0.f) ? (1.f / s) : 0.f;   // deg-0 -> relu(bias)
        half4 hv;
        hv[0] = (_Float16)fmaxf(acc.x * inv + b4.x, 0.f);
        hv[1] = (_Float16)fmaxf(acc.y * inv + b4.y, 0.f);
        hv[2] = (_Float16)fmaxf(acc.z * inv + b4.z, 0.f);
        hv[3] = (_Float16)fmaxf(acc.w * inv + b4.w, 0.f);
        __builtin_nontemporal_store(hv, (half4*)(out + (size_t)d * 64) + l);
    }
}

// ---------------- per-graph mean pool + final linear (no atomics) ---------
// block g = graph g; batch is sorted -> binary search node range.
__global__ __launch_bounds__(256) void pool_final_kernel(
    const _Float16* __restrict__ h, const int* __restrict__ batch,
    const float* __restrict__ lin_w, const float* __restrict__ lin_b,
    float* __restrict__ out, int N, int G) {
    int g = blockIdx.x;
    int t = threadIdx.x;
    // lower_bound(batch, key)
    auto lb = [&](int key) {
        int lo = 0, hi = N;
        while (lo < hi) {
            int mid = (lo + hi) >> 1;
            if (batch[mid] < key) lo = mid + 1; else hi = mid;
        }
        return lo;
    };
    int start = lb(g), end = lb(g + 1);

    __shared__ float part[4][64];
    __shared__ float pooled[64];
    int f = t & 63, w = t >> 6;
    float acc = 0.f;
    for (int i = start + w; i < end; i += 4)          // ~25 rows/thread
        acc += (float)__builtin_nontemporal_load(&h[(size_t)i * 64 + f]);
    part[w][f] = acc;
    __syncthreads();
    if (t < 64) {
        float s = part[0][t] + part[1][t] + part[2][t] + part[3][t];
        pooled[t] = s / fmaxf((float)(end - start), 1.f);
    }
    __syncthreads();
    if (t < 32) {
        float a = 0.f;
#pragma unroll 8
        for (int hh = 0; hh < 64; ++hh) a += pooled[hh] * lin_w[hh * 32 + t];
        out[g * 32 + t] = a + lin_b[t];
    }
}

extern "C" void kernel_launch(void* const* d_in, const int* in_sizes, int n_in,
                              void* d_out, int out_size, void* d_ws, size_t ws_size,
                              hipStream_t stream) {
    const float* x     = (const float*)d_in[0];
    const int*   ei    = (const int*)d_in[1];
    const int*   batch = (const int*)d_in[2];
    const float* Wl1   = (const float*)d_in[3];
    const float* bl1   = (const float*)d_in[4];
    const float* Wr1   = (const float*)d_in[5];
    const float* br1   = (const float*)d_in[6];
    const float* att1  = (const float*)d_in[7];
    const float* bias1 = (const float*)d_in[8];
    const float* Wl2   = (const float*)d_in[9];
    const float* bl2   = (const float*)d_in[10];
    const float* Wr2   = (const float*)d_in[11];
    const float* br2   = (const float*)d_in[12];
    const float* att2  = (const float*)d_in[13];
    const float* bias2 = (const float*)d_in[14];
    const float* lin_w = (const float*)d_in[15];
    const float* lin_b = (const float*)d_in[16];
    float* out = (float*)d_out;

    const int N = in_sizes[0] / 64;
    const int E = in_sizes[1] / 2;
    const int G = out_size / 32;
    const int* src = ei;
    const int* dst = ei + E;

    // ---- workspace carve-up (256B-aligned) ----
    char*  ws  = (char*)d_ws;
    size_t off = 0;
    auto alloc = [&](size_t bytes) -> void* {
        void* p = ws + off;
        off += bytes;
        off = (off + 255) & ~(size_t)255;
        return p;
    };
    _Float16* xl   = (_Float16*)alloc((size_t)N * 64 * sizeof(_Float16));
    float* xr      = (float*)alloc((size_t)N * 64 * sizeof(float));
    _Float16* h1   = (_Float16*)alloc((size_t)N * 64 * sizeof(_Float16));  // h1/h2
    // zeroed region (contiguous): cnt, novf
    int*   cnt     = (int*)alloc((size_t)N * sizeof(int));
    int*   novf    = (int*)alloc(256);
    char*  zend    = ws + off;
    unsigned short* ell = (unsigned short*)alloc((size_t)N * ELLC * sizeof(unsigned short));
    int*   ovf_dst = (int*)alloc((size_t)OVF_CAP * sizeof(int));
    int*   ovf_src = (int*)alloc((size_t)OVF_CAP * sizeof(int));

    (void)hipMemsetAsync(cnt, 0, (size_t)(zend - (char*)cnt), stream);

    int ggrid  = (N + GROWS - 1) / GROWS;
    int agrid  = (N + 3) / 4;                    // one wave per dst node
    int nchunk = (E + ECHUNK - 1) / ECHUNK;
    int fb     = nchunk * 8;                     // fill virtual blocks (x8 XCD)
    int psize  = (N + 7) / 8;                    // dst partition size
    // interleaved grid: groups of 24 = 16 fill + 8 gemm
    int ngroups = max((fb + 15) / 16, (ggrid + 7) / 8);
    int igrid   = ngroups * 24;

    // ---- interleaved: XCD-partitioned ELL fill + layer-1 dual GEMM ----
    fill_gemm_kernel<<<igrid, 256, 0, stream>>>(
        src, dst, cnt, ell, novf, ovf_dst, ovf_src, E, N, psize, fb, ggrid,
        x, Wl1, bl1, Wr1, br1, xl, xr);

    // ---- agg1 -> h1 (fp16) ----
    gat_aggregate_kernel<<<agrid, 256, 0, stream>>>(
        xl, xr, cnt, ell, novf, ovf_dst, ovf_src, att1, bias1, h1, N);

    // ---- layer 2 GEMM (fp16 input; h1 consumed, xl/xr overwritten) ----
    dual_gemm64_f16_kernel<<<ggrid, 256, 0, stream>>>(
        h1, Wl2, bl2, Wr2, br2, xl, xr, N);

    // ---- agg2 -> h1 (fp16, reused) ----
    gat_aggregate_kernel<<<agrid, 256, 0, stream>>>(
        xl, xr, cnt, ell, novf, ovf_dst, ovf_src, att2, bias2, h1, N);

    // ---- per-graph pool + final linear (one dispatch, no atomics) ----
    pool_final_kernel<<<G, 256, 0, stream>>>(h1, batch, lin_w, lin_b, out, N, G);
}

// Round 5
// 247.931 us; speedup vs baseline: 1.0598x; 1.0297x over previous
//
#include <hip/hip_runtime.h>
#include <hip/hip_fp16.h>
#include <math.h>

// ---------------------------------------------------------------------------
// GATv2 x2 + mean-pool + linear, MI355X.
// R25: fuse agg1 + gemm2. agg1's sole consumer is gemm2 (32-row tiles of h1).
//      One block now computes 32 dst rows (4 waves x 8 sequential dst),
//      writes h1 rows into LDS (f32), syncs, and runs the layer-2 dual-GEMM
//      from LDS. Deletes: gemm2 dispatch + bubble, h1 6.4MB write + 6.4MB
//      read. Layer-2 staging goes to a separate xl2/xr2 set (fused kernel
//      still reads xl1 via gathers everywhere -> can't overwrite in place).
//      Fill theories retired after R21-R24 nulls (NT, MLP, atomic scope all
//      neutral): fill ~53us treated as atomic-path floor, left unchanged.
//      Base = R20/R24 (247-255us).
// ---------------------------------------------------------------------------

#define ELLC    48
#define OVF_CAP 65536
#define ECHUNK  2048          // edges per fill virtual block

typedef int      vint4 __attribute__((ext_vector_type(4)));
typedef _Float16 half4 __attribute__((ext_vector_type(4)));
typedef float    f32x4 __attribute__((ext_vector_type(4)));

#define GROWS 32

// ---------------- GEMM pieces: stage (global f32 -> LDS) and compute ------
__device__ __forceinline__ void stage_rows_f32(
    int row0, int t, const float* __restrict__ X, int n, float* xS) {
    for (int i = t; i < GROWS * 16; i += 256) {
        int r = row0 + (i >> 4);
        f32x4 v;
        v[0] = 0.f; v[1] = 0.f; v[2] = 0.f; v[3] = 0.f;
        if (r < n)
            v = __builtin_nontemporal_load(
                &((const f32x4*)(X + (size_t)r * 64))[i & 15]);
        ((f32x4*)xS)[i] = v;
    }
}

// xl = relu-input * Wl + bl (fp16 out), xr = * Wr + br (f32 out), from xS.
__device__ __forceinline__ void gemm_compute(
    int row0, int t,
    const float* __restrict__ Wl, const float* __restrict__ bl,
    const float* __restrict__ Wr, const float* __restrict__ br,
    _Float16* __restrict__ xl, float* __restrict__ xr, int n,
    const float* xS) {
    int h  = t & 63;
    int rb = t >> 6;  // 0..3
    float accl[8], accr[8];
#pragma unroll
    for (int i = 0; i < 8; ++i) { accl[i] = 0.f; accr[i] = 0.f; }
#pragma unroll 4
    for (int d = 0; d < 64; ++d) {
        float wl = Wl[d * 64 + h];   // coalesced 256B, L2-hot
        float wr = Wr[d * 64 + h];
#pragma unroll
        for (int i = 0; i < 8; ++i) {
            float xv = xS[(rb + 4 * i) * 64 + d];  // wave-uniform broadcast
            accl[i] += xv * wl;
            accr[i] += xv * wr;
        }
    }
    float blv = bl[h], brv = br[h];
#pragma unroll
    for (int i = 0; i < 8; ++i) {
        int r = row0 + rb + 4 * i;
        if (r < n) {
            __builtin_nontemporal_store((_Float16)(accl[i] + blv),
                                        &xl[(size_t)r * 64 + h]);
            __builtin_nontemporal_store(accr[i] + brv,
                                        &xr[(size_t)r * 64 + h]);
        }
    }
}

// ---------------- interleaved: XCD-partitioned ELL fill + layer-1 GEMM ----
// 24-block groups: r = b%24. r<16 -> fill vb = (b/24)*16+r (vb&7 == b&7!);
// r>=16 -> gemm vg = (b/24)*8 + (r-16).
__global__ __launch_bounds__(256) void fill_gemm_kernel(
    const int* __restrict__ src, const int* __restrict__ dst,
    int* __restrict__ cnt, unsigned short* __restrict__ ell,
    int* __restrict__ novf, int* __restrict__ ovf_dst, int* __restrict__ ovf_src,
    int E, int N, int psize, int fb, int ggrid,
    const float* __restrict__ X,
    const float* __restrict__ Wl, const float* __restrict__ bl,
    const float* __restrict__ Wr, const float* __restrict__ br,
    _Float16* __restrict__ xl, float* __restrict__ xr) {
    __shared__ float xS[GROWS * 64];
    int b = blockIdx.x;
    int q = b / 24, r = b % 24;
    if (r >= 16) {
        int vg = q * 8 + (r - 16);
        if (vg < ggrid) {
            stage_rows_f32(vg * GROWS, threadIdx.x, X, N, xS);
            __syncthreads();
            gemm_compute(vg * GROWS, threadIdx.x, Wl, bl, Wr, br, xl, xr, N, xS);
        }
        return;
    }
    int vb = q * 16 + r;
    if (vb >= fb) return;
    int t     = threadIdx.x;
    int chunk = vb >> 3;
    int p     = vb & 7;                   // partition == XCD (== b&7)
    int d0    = p * psize;
    int d1    = min(N, d0 + psize);
    int e0    = chunk * ECHUNK;
    int e1    = min(E, e0 + ECHUNK);
    int nq    = (e1 - e0) >> 2;
    const vint4* dst4 = (const vint4*)(dst + e0);
    const vint4* src4 = (const vint4*)(src + e0);

    auto scatter4 = [&](vint4 dv, vint4 sv) {
#pragma unroll
        for (int k = 0; k < 4; ++k) {
            int d = dv[k];
            int s = sv[k];
            if (d >= d0 && d < d1) {
                int pos = atomicAdd(&cnt[d], 1);
                if (pos < ELLC) {
                    ell[d * ELLC + pos] = (unsigned short)s;
                } else {  // P(deg>48) ~ 5e-11 per node
                    int j = atomicAdd(novf, 1);
                    if (j < OVF_CAP) { ovf_dst[j] = d; ovf_src[j] = s; }
                }
            }
        }
    };

    if (nq == (ECHUNK >> 2)) {   // full chunk: both loads up front, 8 chains
        vint4 dvA = __builtin_nontemporal_load(&dst4[t]);
        vint4 svA = __builtin_nontemporal_load(&src4[t]);
        vint4 dvB = __builtin_nontemporal_load(&dst4[t + 256]);
        vint4 svB = __builtin_nontemporal_load(&src4[t + 256]);
        scatter4(dvA, svA);
        scatter4(dvB, svB);
    } else {
        for (int qq = t; qq < nq; qq += 256) {
            vint4 dv = __builtin_nontemporal_load(&dst4[qq]);
            vint4 sv = __builtin_nontemporal_load(&src4[qq]);
            scatter4(dv, sv);
        }
        for (int e = e0 + (nq << 2) + t; e < e1; e += 256) {  // E % 4 tail
            int d = dst[e];
            if (d >= d0 && d < d1) {
                int pos = atomicAdd(&cnt[d], 1);
                int s   = src[e];
                if (pos < ELLC) {
                    ell[d * ELLC + pos] = (unsigned short)s;
                } else {
                    int j = atomicAdd(novf, 1);
                    if (j < OVF_CAP) { ovf_dst[j] = d; ovf_src[j] = s; }
                }
            }
        }
    }
}

// ---------------- agg body: one wave computes h-row of dst d --------------
// wave = 4 groups x 16 lanes; returns via (s, acc) -> caller writes.
// g = lane>>4, l = lane&15.
__device__ __forceinline__ void agg_row(
    int d, int lane, int g, int l,
    const _Float16* __restrict__ xl, const float* __restrict__ xr,
    const int* __restrict__ cnt, const unsigned short* __restrict__ ell,
    const int* __restrict__ novf, const int* __restrict__ ovf_dst,
    const int* __restrict__ ovf_src,
    float4 att4, float& s, float4& acc, int& deg_d) {
    deg_d = cnt[d];
    int nd  = min(deg_d, ELLC);
    int beg = d * ELLC;
    s = 0.f;
    acc = make_float4(0.f, 0.f, 0.f, 0.f);
    if (deg_d <= 0) return;

    // one coalesced 96B read of the whole ELL row; lane i holds slot i
    int myidx = 0;
    if (lane < ELLC)
        myidx = (int)__builtin_nontemporal_load(&ell[beg + lane]);
    int i_first = __shfl(myidx, 0);

    f32x4 xrt = __builtin_nontemporal_load(
        &((const f32x4*)(xr + (size_t)d * 64))[l]);
    float4 xr4 = make_float4(xrt[0], xrt[1], xrt[2], xrt[3]);

#pragma unroll 6
    for (int k = 0; k * 8 < nd; ++k) {     // k < 6 (nd <= 48); uniform
        int  sa = k * 8 + g, sb = sa + 4;
        bool aa = sa < nd,   ab = sb < nd;
        int  i0 = __shfl(myidx, sa); if (!aa) i0 = i_first;
        int  i1 = __shfl(myidx, sb); if (!ab) i1 = i_first;
        half4 h0 = ((const half4*)(xl + (size_t)i0 * 64))[l];  // 8B gather
        half4 h1 = ((const half4*)(xl + (size_t)i1 * 64))[l];
        float4 x0 = make_float4((float)h0[0], (float)h0[1], (float)h0[2], (float)h0[3]);
        float4 x1 = make_float4((float)h1[0], (float)h1[1], (float)h1[2], (float)h1[3]);
        float z, c0 = 0.f, c1 = 0.f;
        z = x0.x + xr4.x; c0 += ((z > 0.f) ? z : 0.2f * z) * att4.x;
        z = x0.y + xr4.y; c0 += ((z > 0.f) ? z : 0.2f * z) * att4.y;
        z = x0.z + xr4.z; c0 += ((z > 0.f) ? z : 0.2f * z) * att4.z;
        z = x0.w + xr4.w; c0 += ((z > 0.f) ? z : 0.2f * z) * att4.w;
        z = x1.x + xr4.x; c1 += ((z > 0.f) ? z : 0.2f * z) * att4.x;
        z = x1.y + xr4.y; c1 += ((z > 0.f) ? z : 0.2f * z) * att4.y;
        z = x1.z + xr4.z; c1 += ((z > 0.f) ? z : 0.2f * z) * att4.z;
        z = x1.w + xr4.w; c1 += ((z > 0.f) ? z : 0.2f * z) * att4.w;
#pragma unroll
        for (int sh = 8; sh >= 1; sh >>= 1) {  // 16-lane reduce
            c0 += __shfl_xor(c0, sh);
            c1 += __shfl_xor(c1, sh);
        }
        float w0 = aa ? __expf(fminf(c0, 30.f)) : 0.f;
        float w1 = ab ? __expf(fminf(c1, 30.f)) : 0.f;
        s += w0 + w1;
        acc.x += w0 * x0.x + w1 * x1.x;
        acc.y += w0 * x0.y + w1 * x1.y;
        acc.z += w0 * x0.z + w1 * x1.z;
        acc.w += w0 * x0.w + w1 * x1.w;
    }
    // overflow fold (deg > ELLC): empty in practice
    if (deg_d > ELLC) {
        int no = min(*novf, OVF_CAP);
        for (int j = g; j < no; j += 4) {
            bool active = (ovf_dst[j] == d);
            int  i0     = active ? ovf_src[j] : i_first;
            half4 h0 = ((const half4*)(xl + (size_t)i0 * 64))[l];
            float4 x0 = make_float4((float)h0[0], (float)h0[1], (float)h0[2], (float)h0[3]);
            f32x4 xrt2 = ((const f32x4*)(xr + (size_t)d * 64))[l];
            float z, c0 = 0.f;
            z = x0.x + xrt2[0]; c0 += ((z > 0.f) ? z : 0.2f * z) * att4.x;
            z = x0.y + xrt2[1]; c0 += ((z > 0.f) ? z : 0.2f * z) * att4.y;
            z = x0.z + xrt2[2]; c0 += ((z > 0.f) ? z : 0.2f * z) * att4.z;
            z = x0.w + xrt2[3]; c0 += ((z > 0.f) ? z : 0.2f * z) * att4.w;
#pragma unroll
            for (int sh = 8; sh >= 1; sh >>= 1) c0 += __shfl_xor(c0, sh);
            float w0 = active ? __expf(fminf(c0, 30.f)) : 0.f;
            s += w0;
            acc.x += w0 * x0.x;
            acc.y += w0 * x0.y;
            acc.z += w0 * x0.z;
            acc.w += w0 * x0.w;
        }
    }
    // merge the 4 group partial sums, xor 16 then xor 32
#pragma unroll
    for (int mask = 16; mask <= 32; mask <<= 1) {
        s     += __shfl_xor(s, mask);
        acc.x += __shfl_xor(acc.x, mask);
        acc.y += __shfl_xor(acc.y, mask);
        acc.z += __shfl_xor(acc.z, mask);
        acc.w += __shfl_xor(acc.w, mask);
    }
}

// ---------------- fused: agg1 (32 dst rows -> LDS) + layer-2 dual GEMM ----
// block = 32 consecutive dst rows; 4 waves x 8 sequential dst each.
__global__ __launch_bounds__(256) void agg_gemm_kernel(
    const _Float16* __restrict__ xl1, const float* __restrict__ xr1,
    const int* __restrict__ cnt, const unsigned short* __restrict__ ell,
    const int* __restrict__ novf, const int* __restrict__ ovf_dst,
    const int* __restrict__ ovf_src,
    const float* __restrict__ att, const float* __restrict__ bias,
    const float* __restrict__ Wl2, const float* __restrict__ bl2,
    const float* __restrict__ Wr2, const float* __restrict__ br2,
    _Float16* __restrict__ xl2, float* __restrict__ xr2, int n) {
    __shared__ float xS[GROWS * 64];
    int t    = threadIdx.x;
    int w    = t >> 6;
    int lane = t & 63;
    int g    = lane >> 4;
    int l    = lane & 15;
    int row0 = blockIdx.x * GROWS;

    float4 att4 = ((const float4*)att)[l];
    float4 b4   = ((const float4*)bias)[l];

    // ---- phase 1: each wave aggregates 8 dst rows into LDS (f32, relu'd) --
    for (int i = 0; i < 8; ++i) {
        int rr = w * 8 + i;
        int d  = row0 + rr;
        float s; float4 acc; int deg_d;
        if (d < n) {
            agg_row(d, lane, g, l, xl1, xr1, cnt, ell, novf, ovf_dst, ovf_src,
                    att4, s, acc, deg_d);
        } else { s = 0.f; acc = make_float4(0.f, 0.f, 0.f, 0.f); }
        if (g == 0) {
            float4 hv = make_float4(0.f, 0.f, 0.f, 0.f);
            if (d < n) {
                float inv = (s > 0.f) ? (1.f / s) : 0.f;  // deg-0 -> relu(bias)
                hv.x = fmaxf(acc.x * inv + b4.x, 0.f);
                hv.y = fmaxf(acc.y * inv + b4.y, 0.f);
                hv.z = fmaxf(acc.z * inv + b4.z, 0.f);
                hv.w = fmaxf(acc.w * inv + b4.w, 0.f);
            }
            ((float4*)(xS + rr * 64))[l] = hv;
        }
    }
    __syncthreads();
    // ---- phase 2: layer-2 dual GEMM straight from LDS ----
    gemm_compute(row0, t, Wl2, bl2, Wr2, br2, xl2, xr2, n, xS);
}

// ---------------- standalone per-dst aggregation (agg2) -------------------
__global__ __launch_bounds__(256) void gat_aggregate_kernel(
    const _Float16* __restrict__ xl, const float* __restrict__ xr,
    const int* __restrict__ cnt, const unsigned short* __restrict__ ell,
    const int* __restrict__ novf, const int* __restrict__ ovf_dst,
    const int* __restrict__ ovf_src,
    const float* __restrict__ att, const float* __restrict__ bias,
    _Float16* __restrict__ out, int n) {
    int wid  = (blockIdx.x * blockDim.x + threadIdx.x) >> 6;
    int lane = threadIdx.x & 63;
    if (wid >= n) return;
    int g = lane >> 4;
    int l = lane & 15;
    float4 att4 = ((const float4*)att)[l];
    float4 b4   = ((const float4*)bias)[l];
    float s; float4 acc; int deg_d;
    agg_row(wid, lane, g, l, xl, xr, cnt, ell, novf, ovf_dst, ovf_src,
            att4, s, acc, deg_d);
    if (g == 0) {
        float inv = (s > 0.f) ? (1.f / s) : 0.f;   // deg-0 -> relu(bias)
        half4 hv;
        hv[0] = (_Float16)fmaxf(acc.x * inv + b4.x, 0.f);
        hv[1] = (_Float16)fmaxf(acc.y * inv + b4.y, 0.f);
        hv[2] = (_Float16)fmaxf(acc.z * inv + b4.z, 0.f);
        hv[3] = (_Float16)fmaxf(acc.w * inv + b4.w, 0.f);
        __builtin_nontemporal_store(hv, (half4*)(out + (size_t)wid * 64) + l);
    }
}

// ---------------- per-graph mean pool + final linear (no atomics) ---------
// block g = graph g; batch is sorted -> binary search node range.
__global__ __launch_bounds__(256) void pool_final_kernel(
    const _Float16* __restrict__ h, const int* __restrict__ batch,
    const float* __restrict__ lin_w, const float* __restrict__ lin_b,
    float* __restrict__ out, int N, int G) {
    int g = blockIdx.x;
    int t = threadIdx.x;
    auto lb = [&](int key) {
        int lo = 0, hi = N;
        while (lo < hi) {
            int mid = (lo + hi) >> 1;
            if (batch[mid] < key) lo = mid + 1; else hi = mid;
        }
        return lo;
    };
    int start = lb(g), end = lb(g + 1);

    __shared__ float part[4][64];
    __shared__ float pooled[64];
    int f = t & 63, w = t >> 6;
    float acc = 0.f;
    for (int i = start + w; i < end; i += 4)          // ~25 rows/thread
        acc += (float)__builtin_nontemporal_load(&h[(size_t)i * 64 + f]);
    part[w][f] = acc;
    __syncthreads();
    if (t < 64) {
        float s = part[0][t] + part[1][t] + part[2][t] + part[3][t];
        pooled[t] = s / fmaxf((float)(end - start), 1.f);
    }
    __syncthreads();
    if (t < 32) {
        float a = 0.f;
#pragma unroll 8
        for (int hh = 0; hh < 64; ++hh) a += pooled[hh] * lin_w[hh * 32 + t];
        out[g * 32 + t] = a + lin_b[t];
    }
}

extern "C" void kernel_launch(void* const* d_in, const int* in_sizes, int n_in,
                              void* d_out, int out_size, void* d_ws, size_t ws_size,
                              hipStream_t stream) {
    const float* x     = (const float*)d_in[0];
    const int*   ei    = (const int*)d_in[1];
    const int*   batch = (const int*)d_in[2];
    const float* Wl1   = (const float*)d_in[3];
    const float* bl1   = (const float*)d_in[4];
    const float* Wr1   = (const float*)d_in[5];
    const float* br1   = (const float*)d_in[6];
    const float* att1  = (const float*)d_in[7];
    const float* bias1 = (const float*)d_in[8];
    const float* Wl2   = (const float*)d_in[9];
    const float* bl2   = (const float*)d_in[10];
    const float* Wr2   = (const float*)d_in[11];
    const float* br2   = (const float*)d_in[12];
    const float* att2  = (const float*)d_in[13];
    const float* bias2 = (const float*)d_in[14];
    const float* lin_w = (const float*)d_in[15];
    const float* lin_b = (const float*)d_in[16];
    float* out = (float*)d_out;

    const int N = in_sizes[0] / 64;
    const int E = in_sizes[1] / 2;
    const int G = out_size / 32;
    const int* src = ei;
    const int* dst = ei + E;

    // ---- workspace carve-up (256B-aligned) ----
    char*  ws  = (char*)d_ws;
    size_t off = 0;
    auto alloc = [&](size_t bytes) -> void* {
        void* p = ws + off;
        off += bytes;
        off = (off + 255) & ~(size_t)255;
        return p;
    };
    _Float16* xl1  = (_Float16*)alloc((size_t)N * 64 * sizeof(_Float16));
    float* xr1     = (float*)alloc((size_t)N * 64 * sizeof(float));
    _Float16* xl2  = (_Float16*)alloc((size_t)N * 64 * sizeof(_Float16));
    float* xr2     = (float*)alloc((size_t)N * 64 * sizeof(float));
    _Float16* h2   = (_Float16*)alloc((size_t)N * 64 * sizeof(_Float16));
    // zeroed region (contiguous): cnt, novf
    int*   cnt     = (int*)alloc((size_t)N * sizeof(int));
    int*   novf    = (int*)alloc(256);
    char*  zend    = ws + off;
    unsigned short* ell = (unsigned short*)alloc((size_t)N * ELLC * sizeof(unsigned short));
    int*   ovf_dst = (int*)alloc((size_t)OVF_CAP * sizeof(int));
    int*   ovf_src = (int*)alloc((size_t)OVF_CAP * sizeof(int));

    (void)hipMemsetAsync(cnt, 0, (size_t)(zend - (char*)cnt), stream);

    int ggrid  = (N + GROWS - 1) / GROWS;        // 32-row tiles
    int agrid  = (N + 3) / 4;                    // one wave per dst node
    int nchunk = (E + ECHUNK - 1) / ECHUNK;
    int fb     = nchunk * 8;                     // fill virtual blocks (x8 XCD)
    int psize  = (N + 7) / 8;                    // dst partition size
    // interleaved grid: groups of 24 = 16 fill + 8 gemm
    int ngroups = max((fb + 15) / 16, (ggrid + 7) / 8);
    int igrid   = ngroups * 24;

    // ---- interleaved: XCD-partitioned ELL fill + layer-1 dual GEMM ----
    fill_gemm_kernel<<<igrid, 256, 0, stream>>>(
        src, dst, cnt, ell, novf, ovf_dst, ovf_src, E, N, psize, fb, ggrid,
        x, Wl1, bl1, Wr1, br1, xl1, xr1);

    // ---- fused agg1 (-> LDS) + layer-2 dual GEMM (-> xl2/xr2) ----
    agg_gemm_kernel<<<ggrid, 256, 0, stream>>>(
        xl1, xr1, cnt, ell, novf, ovf_dst, ovf_src, att1, bias1,
        Wl2, bl2, Wr2, br2, xl2, xr2, N);

    // ---- agg2 -> h2 (fp16) ----
    gat_aggregate_kernel<<<agrid, 256, 0, stream>>>(
        xl2, xr2, cnt, ell, novf, ovf_dst, ovf_src, att2, bias2, h2, N);

    // ---- per-graph pool + final linear (one dispatch, no atomics) ----
    pool_final_kernel<<<G, 256, 0, stream>>>(h2, batch, lin_w, lin_b, out, N, G);
}